// Round 2
// baseline (344.038 us; speedup 1.0000x reference)
//
#include <hip/hip_runtime.h>
#include <hip/hip_bf16.h>
#include <stdint.h>

#define T_LEN 8192
#define DIN   1024
#define DOUT  1024
#define TRACE 64
#define CTX   16
#define KTOT  3072      // DIN + 2*TRACE*CTX
#define CH    64        // scan chunk length
#define NCHUNK 128      // T_LEN / CH
#define LDT   40        // padded LDS row length in shorts (80 B)

using bf16 = __hip_bfloat16;
typedef __attribute__((ext_vector_type(4))) float f32x4;
typedef __attribute__((ext_vector_type(8))) short s16x8;

// ---------------- f32 -> bf16 strided convert ----------------
__global__ void cvt_cast(const float* __restrict__ src, bf16* __restrict__ dst,
                         int rows, int cols, int dst_ld, int dst_coff) {
    int idx4 = blockIdx.x * blockDim.x + threadIdx.x;
    int cpr = cols >> 2;
    int total4 = rows * cpr;
    if (idx4 >= total4) return;
    int r  = idx4 / cpr;
    int c4 = (idx4 - r * cpr) << 2;
    float4 v = *(const float4*)(src + (size_t)r * cols + c4);
    union { bf16 h[4]; uint2 u; } pk;
    pk.h[0] = __float2bfloat16(v.x); pk.h[1] = __float2bfloat16(v.y);
    pk.h[2] = __float2bfloat16(v.z); pk.h[3] = __float2bfloat16(v.w);
    *(uint2*)(dst + (size_t)r * dst_ld + dst_coff + c4) = pk.u;
}

// ---------------- pre-GEMM: pre_raw[8192][64] = x @ W_pre^T + b_pre ----------------
__global__ __launch_bounds__(256) void gemm_pre(const bf16* __restrict__ A,   // [8192][KTOT], k in [0,1024)
                                                const bf16* __restrict__ B,   // [64][1024]
                                                const float* __restrict__ bpre,
                                                float* __restrict__ out) {    // [8192][64]
    __shared__ short As[2][128 * LDT];
    __shared__ short Bs[2][64 * LDT];
    const int tid = threadIdx.x;
    const int lane = tid & 63, wv = tid >> 6;
    const int wm = wv >> 1, wn = wv & 1;
    const int row0 = blockIdx.x * 128;

    int4 ra[2]; int4 rb;
    auto gload = [&](int kt) {
#pragma unroll
        for (int j = 0; j < 2; ++j) {
            int li = tid + j * 256;
            int r = li >> 2, c = (li & 3) * 8;
            ra[j] = *(const int4*)(A + (size_t)(row0 + r) * KTOT + kt * 32 + c);
        }
        { int r = tid >> 2, c = (tid & 3) * 8;
          rb = *(const int4*)(B + (size_t)r * 1024 + kt * 32 + c); }
    };
    auto swrite = [&](int buf) {
#pragma unroll
        for (int j = 0; j < 2; ++j) {
            int li = tid + j * 256;
            int r = li >> 2, c = (li & 3) * 8;
            *(int4*)&As[buf][r * LDT + c] = ra[j];
        }
        { int r = tid >> 2, c = (tid & 3) * 8;
          *(int4*)&Bs[buf][r * LDT + c] = rb; }
    };

    f32x4 acc[4][2];
#pragma unroll
    for (int i = 0; i < 4; ++i)
#pragma unroll
        for (int j = 0; j < 2; ++j) acc[i][j] = (f32x4)0.0f;

    gload(0); swrite(0);
    int buf = 0;
    const int NT = 1024 / 32;  // 32
    for (int kt = 0; kt < NT; ++kt) {
        if (kt + 1 < NT) gload(kt + 1);
        __syncthreads();
        const int lr = lane & 15, lk = (lane >> 4) * 8;
        s16x8 af[4], bfr[2];
#pragma unroll
        for (int i = 0; i < 4; ++i)
            af[i] = *(const s16x8*)&As[buf][(wm * 64 + i * 16 + lr) * LDT + lk];
#pragma unroll
        for (int j = 0; j < 2; ++j)
            bfr[j] = *(const s16x8*)&Bs[buf][(wn * 32 + j * 16 + lr) * LDT + lk];
#pragma unroll
        for (int i = 0; i < 4; ++i)
#pragma unroll
            for (int j = 0; j < 2; ++j)
                acc[i][j] = __builtin_amdgcn_mfma_f32_16x16x32_bf16(af[i], bfr[j], acc[i][j], 0, 0, 0);
        if (kt + 1 < NT) swrite(buf ^ 1);
        buf ^= 1;
    }
    const int lr = lane & 15, lg = lane >> 4;
#pragma unroll
    for (int j = 0; j < 2; ++j) {
        int col = wn * 32 + j * 16 + lr;
        float bias = bpre[col];
#pragma unroll
        for (int i = 0; i < 4; ++i) {
            int rbase = row0 + wm * 64 + i * 16 + lg * 4;
#pragma unroll
            for (int r = 0; r < 4; ++r)
                out[(size_t)(rbase + r) * TRACE + col] = acc[i][j][r] + bias;
        }
    }
}

// ---------------- scan phase 1: per-chunk local scan (zero init) ----------------
__global__ void scan_phase1(const float* __restrict__ pre_raw, const int* __restrict__ start,
                            const float* __restrict__ a, const float* __restrict__ bfreq,
                            float2* __restrict__ local_end, int* __restrict__ reset_any) {
    __shared__ float pn[CH][TRACE + 1];
    __shared__ float rn[CH];
    __shared__ int sf[CH];
    const int k = blockIdx.x, tid = threadIdx.x;
    for (int idx = tid; idx < CH * TRACE; idx += 256) {
        int r = idx >> 6, m = idx & 63;
        pn[r][m] = pre_raw[(size_t)(k * CH + r) * TRACE + m];
    }
    if (tid < CH) sf[tid] = start[k * CH + tid];
    __syncthreads();
    if (tid < CH) {
        float s = 0.f;
#pragma unroll
        for (int m = 0; m < TRACE; ++m) { float v = pn[tid][m]; s += v * v; }
        rn[tid] = 1.0f / (1e-6f + sqrtf(s));
    }
    if (tid == 0) { int any = 0; for (int r = 0; r < CH; ++r) any |= sf[r]; reset_any[k] = any; }
    __syncthreads();
#pragma unroll
    for (int q = 0; q < 4; ++q) {
        int pair = tid + q * 256;
        int m = pair >> 4, c = pair & 15;
        float am = a[m], th = bfreq[c];
        float e = expf(-fabsf(am));
        float sn, cs; sincosf(th, &sn, &cs);
        float gr = e * cs, gi = e * sn;
        float sre = 0.f, sim = 0.f;
        for (int r = 0; r < CH; ++r) {
            float p = pn[r][m] * rn[r];
            if (sf[r]) { sre = p; sim = 0.f; }
            else { float t = gr * sre - gi * sim + p; sim = gr * sim + gi * sre; sre = t; }
        }
        local_end[(size_t)k * 1024 + pair] = make_float2(sre, sim);
    }
}

// ---------------- scan phase 2: sequential carry over chunks ----------------
// Tail layout: PLANAR — out_tail[0..1023] = re(m*16+c), out_tail[1024..2047] = im.
__global__ void scan_phase2(const float2* __restrict__ local_end, const int* __restrict__ reset_any,
                            const float* __restrict__ state_re, const float* __restrict__ state_im,
                            const float* __restrict__ a, const float* __restrict__ bfreq,
                            float2* __restrict__ carry_in, float* __restrict__ out_tail, int tail_n) {
    const int pair = threadIdx.x;  // 1024 threads
    const int m = pair >> 4, c = pair & 15;
    float am = a[m], th = bfreq[c];
    float e = expf(-64.f * fabsf(am));
    float sn, cs; sincosf(64.f * th, &sn, &cs);
    float gr = e * cs, gi = e * sn;
    float cre = state_re[pair], cim = state_im[pair];
    for (int k = 0; k < NCHUNK; ++k) {
        carry_in[(size_t)k * 1024 + pair] = make_float2(cre, cim);
        float2 le = local_end[(size_t)k * 1024 + pair];
        if (reset_any[k]) { cre = le.x; cim = le.y; }
        else {
            float t = gr * cre - gi * cim + le.x;
            cim = gr * cim + gi * cre + le.y;
            cre = t;
        }
    }
    if (pair < tail_n)        out_tail[pair]        = cre;
    if (1024 + pair < tail_n) out_tail[1024 + pair] = cim;
}

// ---------------- scan phase 3: recompute with carry, emit bf16 z_in ----------------
__global__ void scan_phase3(const float* __restrict__ pre_raw, const int* __restrict__ start,
                            const float* __restrict__ a, const float* __restrict__ bfreq,
                            const float2* __restrict__ carry_in, bf16* __restrict__ A) {
    __shared__ float pn[CH][TRACE + 1];
    __shared__ float rn[CH];
    __shared__ int sf[CH];
    const int k = blockIdx.x, tid = threadIdx.x;
    for (int idx = tid; idx < CH * TRACE; idx += 256) {
        int r = idx >> 6, m = idx & 63;
        pn[r][m] = pre_raw[(size_t)(k * CH + r) * TRACE + m];
    }
    if (tid < CH) sf[tid] = start[k * CH + tid];
    __syncthreads();
    if (tid < CH) {
        float s = 0.f;
#pragma unroll
        for (int m = 0; m < TRACE; ++m) { float v = pn[tid][m]; s += v * v; }
        rn[tid] = 1.0f / (1e-6f + sqrtf(s));
    }
    __syncthreads();
#pragma unroll
    for (int q = 0; q < 4; ++q) {
        int pair = tid + q * 256;
        int m = pair >> 4, c = pair & 15;
        float am = a[m], th = bfreq[c];
        float e = expf(-fabsf(am));
        float sn, cs; sincosf(th, &sn, &cs);
        float gr = e * cs, gi = e * sn;
        float2 ci = carry_in[(size_t)k * 1024 + pair];
        float sre = ci.x, sim = ci.y;
        for (int r = 0; r < CH; ++r) {
            float p = pn[r][m] * rn[r];
            if (sf[r]) { sre = p; sim = 0.f; }
            else { float t = gr * sre - gi * sim + p; sim = gr * sim + gi * sre; sre = t; }
            size_t rowoff = (size_t)(k * CH + r) * KTOT;
            A[rowoff + 1024 + m * 32 + c]      = __float2bfloat16(sre);
            A[rowoff + 1024 + m * 32 + 16 + c] = __float2bfloat16(sim);
        }
    }
}

// ---------------- main GEMM: out = [x|z] @ [W_skip|W_mix]^T + bias ----------------
__global__ __launch_bounds__(256) void gemm_main(const bf16* __restrict__ A,  // [8192][3072]
                                                 const bf16* __restrict__ B,  // [1024][3072]
                                                 const float* __restrict__ bskip,
                                                 const float* __restrict__ bmix,
                                                 float* __restrict__ out) {   // [8192][1024]
    __shared__ short As[2][128 * LDT];
    __shared__ short Bs[2][128 * LDT];
    const int tid = threadIdx.x;
    const int lane = tid & 63, wv = tid >> 6;
    const int wm = wv >> 1, wn = wv & 1;
    const int row0 = blockIdx.y * 128, col0 = blockIdx.x * 128;

    int4 ra[2], rb[2];
    auto gload = [&](int kt) {
#pragma unroll
        for (int j = 0; j < 2; ++j) {
            int li = tid + j * 256;
            int r = li >> 2, c = (li & 3) * 8;
            ra[j] = *(const int4*)(A + (size_t)(row0 + r) * KTOT + kt * 32 + c);
            rb[j] = *(const int4*)(B + (size_t)(col0 + r) * KTOT + kt * 32 + c);
        }
    };
    auto swrite = [&](int buf) {
#pragma unroll
        for (int j = 0; j < 2; ++j) {
            int li = tid + j * 256;
            int r = li >> 2, c = (li & 3) * 8;
            *(int4*)&As[buf][r * LDT + c] = ra[j];
            *(int4*)&Bs[buf][r * LDT + c] = rb[j];
        }
    };

    f32x4 acc[4][4];
#pragma unroll
    for (int i = 0; i < 4; ++i)
#pragma unroll
        for (int j = 0; j < 4; ++j) acc[i][j] = (f32x4)0.0f;

    gload(0); swrite(0);
    int buf = 0;
    const int NT = KTOT / 32;  // 96
    for (int kt = 0; kt < NT; ++kt) {
        if (kt + 1 < NT) gload(kt + 1);
        __syncthreads();
        const int lr = lane & 15, lk = (lane >> 4) * 8;
        s16x8 af[4], bfr[4];
#pragma unroll
        for (int i = 0; i < 4; ++i)
            af[i] = *(const s16x8*)&As[buf][(wm * 64 + i * 16 + lr) * LDT + lk];
#pragma unroll
        for (int j = 0; j < 4; ++j)
            bfr[j] = *(const s16x8*)&Bs[buf][(wn * 64 + j * 16 + lr) * LDT + lk];
#pragma unroll
        for (int i = 0; i < 4; ++i)
#pragma unroll
            for (int j = 0; j < 4; ++j)
                acc[i][j] = __builtin_amdgcn_mfma_f32_16x16x32_bf16(af[i], bfr[j], acc[i][j], 0, 0, 0);
        if (kt + 1 < NT) swrite(buf ^ 1);
        buf ^= 1;
    }
    const int lr = lane & 15, lg = lane >> 4;
#pragma unroll
    for (int j = 0; j < 4; ++j) {
        int col = col0 + wn * 64 + j * 16 + lr;
        float bias = bskip[col] + bmix[col];
#pragma unroll
        for (int i = 0; i < 4; ++i) {
            int rbase = row0 + wm * 64 + i * 16 + lg * 4;
#pragma unroll
            for (int r = 0; r < 4; ++r)
                out[(size_t)(rbase + r) * DOUT + col] = acc[i][j][r] + bias;
        }
    }
}

extern "C" void kernel_launch(void* const* d_in, const int* in_sizes, int n_in,
                              void* d_out, int out_size, void* d_ws, size_t ws_size,
                              hipStream_t stream) {
    const float* x        = (const float*)d_in[0];
    const float* state_re = (const float*)d_in[1];
    const float* state_im = (const float*)d_in[2];
    const int*   start    = (const int*)d_in[3];
    const float* W_pre    = (const float*)d_in[5];
    const float* b_pre    = (const float*)d_in[6];
    const float* W_skip   = (const float*)d_in[7];
    const float* b_skip   = (const float*)d_in[8];
    const float* W_mix    = (const float*)d_in[9];
    const float* b_mix    = (const float*)d_in[10];
    const float* a_dec    = (const float*)d_in[11];
    const float* b_freq   = (const float*)d_in[12];

    uint8_t* ws = (uint8_t*)d_ws;
    bf16*  A         = (bf16*)(ws);                 // 8192*3072*2 = 50331648
    bf16*  Bc        = (bf16*)(ws + 50331648);      // 1024*3072*2 = 6291456
    bf16*  Wp        = (bf16*)(ws + 56623104);      // 64*1024*2   = 131072
    float* pre_raw   = (float*)(ws + 56754176);     // 8192*64*4   = 2097152
    float2* local_end= (float2*)(ws + 58851328);    // 128*1024*8  = 1048576
    float2* carry_in = (float2*)(ws + 59899904);    // 1048576
    int*   reset_any = (int*)(ws + 60948480);       // 512

    cvt_cast<<<dim3((8192 * 1024 / 4 + 255) / 256), 256, 0, stream>>>(x, A, 8192, 1024, KTOT, 0);
    cvt_cast<<<dim3((1024 * 1024 / 4 + 255) / 256), 256, 0, stream>>>(W_skip, Bc, 1024, 1024, KTOT, 0);
    cvt_cast<<<dim3((1024 * 2048 / 4 + 255) / 256), 256, 0, stream>>>(W_mix, Bc, 1024, 2048, KTOT, 1024);
    cvt_cast<<<dim3((64 * 1024 / 4 + 255) / 256), 256, 0, stream>>>(W_pre, Wp, 64, 1024, 1024, 0);

    gemm_pre<<<dim3(64), 256, 0, stream>>>(A, Wp, b_pre, pre_raw);
    scan_phase1<<<dim3(NCHUNK), 256, 0, stream>>>(pre_raw, start, a_dec, b_freq, local_end, reset_any);
    int tail_n = out_size - 8192 * 1024;
    if (tail_n < 0) tail_n = 0;
    if (tail_n > 2048) tail_n = 2048;
    scan_phase2<<<dim3(1), 1024, 0, stream>>>(local_end, reset_any, state_re, state_im, a_dec, b_freq,
                                              carry_in, (float*)d_out + 8192 * 1024, tail_n);
    scan_phase3<<<dim3(NCHUNK), 256, 0, stream>>>(pre_raw, start, a_dec, b_freq, carry_in, A);
    gemm_main<<<dim3(8, 64), 256, 0, stream>>>(A, Bc, b_skip, b_mix, (float*)d_out);
}

// Round 3
// 199.264 us; speedup vs baseline: 1.7265x; 1.7265x over previous
//
#include <hip/hip_runtime.h>
#include <hip/hip_bf16.h>
#include <stdint.h>

#define T_LEN 8192
#define DIN   1024
#define DOUT  1024
#define TRACE 64
#define CTX   16
#define KTOT  3072      // DIN + 2*TRACE*CTX
#define CH    64        // scan chunk length
#define NCHUNK 128      // T_LEN / CH
#define LDT   40        // padded LDS row length in shorts (80 B) — scan/pre kernels only

using bf16 = __hip_bfloat16;
typedef __attribute__((ext_vector_type(4))) float f32x4;
typedef __attribute__((ext_vector_type(8))) short s16x8;

// ---------------- f32 -> bf16 strided convert ----------------
__global__ void cvt_cast(const float* __restrict__ src, bf16* __restrict__ dst,
                         int rows, int cols, int dst_ld, int dst_coff) {
    int idx4 = blockIdx.x * blockDim.x + threadIdx.x;
    int cpr = cols >> 2;
    int total4 = rows * cpr;
    if (idx4 >= total4) return;
    int r  = idx4 / cpr;
    int c4 = (idx4 - r * cpr) << 2;
    float4 v = *(const float4*)(src + (size_t)r * cols + c4);
    union { bf16 h[4]; uint2 u; } pk;
    pk.h[0] = __float2bfloat16(v.x); pk.h[1] = __float2bfloat16(v.y);
    pk.h[2] = __float2bfloat16(v.z); pk.h[3] = __float2bfloat16(v.w);
    *(uint2*)(dst + (size_t)r * dst_ld + dst_coff + c4) = pk.u;
}

// ---------------- pre-GEMM: pre_raw[8192][64] = x @ W_pre^T + b_pre ----------------
__global__ __launch_bounds__(256) void gemm_pre(const bf16* __restrict__ A,   // [8192][KTOT], k in [0,1024)
                                                const bf16* __restrict__ B,   // [64][1024]
                                                const float* __restrict__ bpre,
                                                float* __restrict__ out) {    // [8192][64]
    __shared__ short As[2][128 * LDT];
    __shared__ short Bs[2][64 * LDT];
    const int tid = threadIdx.x;
    const int lane = tid & 63, wv = tid >> 6;
    const int wm = wv >> 1, wn = wv & 1;
    const int row0 = blockIdx.x * 128;

    int4 ra[2]; int4 rb;
    auto gload = [&](int kt) {
#pragma unroll
        for (int j = 0; j < 2; ++j) {
            int li = tid + j * 256;
            int r = li >> 2, c = (li & 3) * 8;
            ra[j] = *(const int4*)(A + (size_t)(row0 + r) * KTOT + kt * 32 + c);
        }
        { int r = tid >> 2, c = (tid & 3) * 8;
          rb = *(const int4*)(B + (size_t)r * 1024 + kt * 32 + c); }
    };
    auto swrite = [&](int buf) {
#pragma unroll
        for (int j = 0; j < 2; ++j) {
            int li = tid + j * 256;
            int r = li >> 2, c = (li & 3) * 8;
            *(int4*)&As[buf][r * LDT + c] = ra[j];
        }
        { int r = tid >> 2, c = (tid & 3) * 8;
          *(int4*)&Bs[buf][r * LDT + c] = rb; }
    };

    f32x4 acc[4][2];
#pragma unroll
    for (int i = 0; i < 4; ++i)
#pragma unroll
        for (int j = 0; j < 2; ++j) acc[i][j] = (f32x4)0.0f;

    gload(0); swrite(0);
    int buf = 0;
    const int NT = 1024 / 32;  // 32
    for (int kt = 0; kt < NT; ++kt) {
        if (kt + 1 < NT) gload(kt + 1);
        __syncthreads();
        const int lr = lane & 15, lk = (lane >> 4) * 8;
        s16x8 af[4], bfr[2];
#pragma unroll
        for (int i = 0; i < 4; ++i)
            af[i] = *(const s16x8*)&As[buf][(wm * 64 + i * 16 + lr) * LDT + lk];
#pragma unroll
        for (int j = 0; j < 2; ++j)
            bfr[j] = *(const s16x8*)&Bs[buf][(wn * 32 + j * 16 + lr) * LDT + lk];
#pragma unroll
        for (int i = 0; i < 4; ++i)
#pragma unroll
            for (int j = 0; j < 2; ++j)
                acc[i][j] = __builtin_amdgcn_mfma_f32_16x16x32_bf16(af[i], bfr[j], acc[i][j], 0, 0, 0);
        if (kt + 1 < NT) swrite(buf ^ 1);
        buf ^= 1;
    }
    const int lr = lane & 15, lg = lane >> 4;
#pragma unroll
    for (int j = 0; j < 2; ++j) {
        int col = wn * 32 + j * 16 + lr;
        float bias = bpre[col];
#pragma unroll
        for (int i = 0; i < 4; ++i) {
            int rbase = row0 + wm * 64 + i * 16 + lg * 4;
#pragma unroll
            for (int r = 0; r < 4; ++r)
                out[(size_t)(rbase + r) * TRACE + col] = acc[i][j][r] + bias;
        }
    }
}

// ---------------- scan phase 1: per-chunk local scan (zero init) ----------------
__global__ void scan_phase1(const float* __restrict__ pre_raw, const int* __restrict__ start,
                            const float* __restrict__ a, const float* __restrict__ bfreq,
                            float2* __restrict__ local_end, int* __restrict__ reset_any) {
    __shared__ float pn[CH][TRACE + 1];
    __shared__ float rn[CH];
    __shared__ int sf[CH];
    const int k = blockIdx.x, tid = threadIdx.x;
    for (int idx = tid; idx < CH * TRACE; idx += 256) {
        int r = idx >> 6, m = idx & 63;
        pn[r][m] = pre_raw[(size_t)(k * CH + r) * TRACE + m];
    }
    if (tid < CH) sf[tid] = start[k * CH + tid];
    __syncthreads();
    if (tid < CH) {
        float s = 0.f;
#pragma unroll
        for (int m = 0; m < TRACE; ++m) { float v = pn[tid][m]; s += v * v; }
        rn[tid] = 1.0f / (1e-6f + sqrtf(s));
    }
    if (tid == 0) { int any = 0; for (int r = 0; r < CH; ++r) any |= sf[r]; reset_any[k] = any; }
    __syncthreads();
#pragma unroll
    for (int q = 0; q < 4; ++q) {
        int pair = tid + q * 256;
        int m = pair >> 4, c = pair & 15;
        float am = a[m], th = bfreq[c];
        float e = expf(-fabsf(am));
        float sn, cs; sincosf(th, &sn, &cs);
        float gr = e * cs, gi = e * sn;
        float sre = 0.f, sim = 0.f;
        for (int r = 0; r < CH; ++r) {
            float p = pn[r][m] * rn[r];
            if (sf[r]) { sre = p; sim = 0.f; }
            else { float t = gr * sre - gi * sim + p; sim = gr * sim + gi * sre; sre = t; }
        }
        local_end[(size_t)k * 1024 + pair] = make_float2(sre, sim);
    }
}

// ---------------- scan phase 2: sequential carry over chunks ----------------
// Tail layout: PLANAR — out_tail[0..1023] = re(m*16+c), out_tail[1024..2047] = im.
__global__ void scan_phase2(const float2* __restrict__ local_end, const int* __restrict__ reset_any,
                            const float* __restrict__ state_re, const float* __restrict__ state_im,
                            const float* __restrict__ a, const float* __restrict__ bfreq,
                            float2* __restrict__ carry_in, float* __restrict__ out_tail, int tail_n) {
    const int pair = threadIdx.x;  // 1024 threads
    const int m = pair >> 4, c = pair & 15;
    float am = a[m], th = bfreq[c];
    float e = expf(-64.f * fabsf(am));
    float sn, cs; sincosf(64.f * th, &sn, &cs);
    float gr = e * cs, gi = e * sn;
    float cre = state_re[pair], cim = state_im[pair];
    for (int k = 0; k < NCHUNK; ++k) {
        carry_in[(size_t)k * 1024 + pair] = make_float2(cre, cim);
        float2 le = local_end[(size_t)k * 1024 + pair];
        if (reset_any[k]) { cre = le.x; cim = le.y; }
        else {
            float t = gr * cre - gi * cim + le.x;
            cim = gr * cim + gi * cre + le.y;
            cre = t;
        }
    }
    if (pair < tail_n)        out_tail[pair]        = cre;
    if (1024 + pair < tail_n) out_tail[1024 + pair] = cim;
}

// ---------------- scan phase 3: recompute with carry, emit bf16 z_in ----------------
__global__ void scan_phase3(const float* __restrict__ pre_raw, const int* __restrict__ start,
                            const float* __restrict__ a, const float* __restrict__ bfreq,
                            const float2* __restrict__ carry_in, bf16* __restrict__ A) {
    __shared__ float pn[CH][TRACE + 1];
    __shared__ float rn[CH];
    __shared__ int sf[CH];
    const int k = blockIdx.x, tid = threadIdx.x;
    for (int idx = tid; idx < CH * TRACE; idx += 256) {
        int r = idx >> 6, m = idx & 63;
        pn[r][m] = pre_raw[(size_t)(k * CH + r) * TRACE + m];
    }
    if (tid < CH) sf[tid] = start[k * CH + tid];
    __syncthreads();
    if (tid < CH) {
        float s = 0.f;
#pragma unroll
        for (int m = 0; m < TRACE; ++m) { float v = pn[tid][m]; s += v * v; }
        rn[tid] = 1.0f / (1e-6f + sqrtf(s));
    }
    __syncthreads();
#pragma unroll
    for (int q = 0; q < 4; ++q) {
        int pair = tid + q * 256;
        int m = pair >> 4, c = pair & 15;
        float am = a[m], th = bfreq[c];
        float e = expf(-fabsf(am));
        float sn, cs; sincosf(th, &sn, &cs);
        float gr = e * cs, gi = e * sn;
        float2 ci = carry_in[(size_t)k * 1024 + pair];
        float sre = ci.x, sim = ci.y;
        for (int r = 0; r < CH; ++r) {
            float p = pn[r][m] * rn[r];
            if (sf[r]) { sre = p; sim = 0.f; }
            else { float t = gr * sre - gi * sim + p; sim = gr * sim + gi * sre; sre = t; }
            size_t rowoff = (size_t)(k * CH + r) * KTOT;
            A[rowoff + 1024 + m * 32 + c]      = __float2bfloat16(sre);
            A[rowoff + 1024 + m * 32 + 16 + c] = __float2bfloat16(sim);
        }
    }
}

// ---------------- main GEMM: out = [x|z] @ [W_skip|W_mix]^T + bias ----------------
// m97 structure: 128x128 tile, BK=32, global_load_lds width-16 into linear LDS,
// 2-phase loop (1 barrier/K-step), XCD-aware block swizzle (512 blocks, 512%8==0).
__global__ __launch_bounds__(256) void gemm_main(const bf16* __restrict__ A,  // [8192][3072]
                                                 const bf16* __restrict__ B,  // [1024][3072]
                                                 const float* __restrict__ bskip,
                                                 const float* __restrict__ bmix,
                                                 float* __restrict__ out) {   // [8192][1024]
    __shared__ short As[2][128 * 32];
    __shared__ short Bs[2][128 * 32];
    const int tid = threadIdx.x;
    const int lane = tid & 63, wv = tid >> 6;
    const int wm = wv >> 1, wn = wv & 1;

    // XCD swizzle: hardware round-robins original blockIdx across 8 XCDs;
    // give each XCD a contiguous 64-tile chunk (shares A row-panels in its L2).
    const int wg  = blockIdx.x;
    const int swz = (wg & 7) * 64 + (wg >> 3);
    const int row0 = (swz >> 3) * 128;   // 64 row tiles
    const int col0 = (swz & 7) * 128;    // 8 col tiles

    const int l4 = lane >> 2;            // row within 16-row chunk
    const int c8 = (lane & 3) * 8;       // short offset within row (4 x 16B)

    auto stage = [&](int kt, int buf) {
#pragma unroll
        for (int j = 0; j < 2; ++j) {
            int chunk = wv * 2 + j;      // 0..7 -> 16-row chunk
            int r = chunk * 16 + l4;
            const bf16* ga = A + (size_t)(row0 + r) * KTOT + kt * 32 + c8;
            const bf16* gb = B + (size_t)(col0 + r) * KTOT + kt * 32 + c8;
            __builtin_amdgcn_global_load_lds(
                (const __attribute__((address_space(1))) void*)ga,
                (__attribute__((address_space(3))) void*)&As[buf][chunk * 512], 16, 0, 0);
            __builtin_amdgcn_global_load_lds(
                (const __attribute__((address_space(1))) void*)gb,
                (__attribute__((address_space(3))) void*)&Bs[buf][chunk * 512], 16, 0, 0);
        }
    };

    f32x4 acc[4][4];
#pragma unroll
    for (int i = 0; i < 4; ++i)
#pragma unroll
        for (int j = 0; j < 4; ++j) acc[i][j] = (f32x4)0.0f;

    stage(0, 0);
    __syncthreads();   // compiler emits vmcnt(0) drain before barrier
    int buf = 0;
    const int lr = lane & 15, lk = (lane >> 4) * 8;
    const int NT = KTOT / 32;  // 96
    for (int kt = 0; kt < NT; ++kt) {
        if (kt + 1 < NT) stage(kt + 1, buf ^ 1);
        s16x8 af[4], bfr[4];
#pragma unroll
        for (int i = 0; i < 4; ++i)
            af[i] = *(const s16x8*)&As[buf][(wm * 64 + i * 16 + lr) * 32 + lk];
#pragma unroll
        for (int j = 0; j < 4; ++j)
            bfr[j] = *(const s16x8*)&Bs[buf][(wn * 64 + j * 16 + lr) * 32 + lk];
#pragma unroll
        for (int i = 0; i < 4; ++i)
#pragma unroll
            for (int j = 0; j < 4; ++j)
                acc[i][j] = __builtin_amdgcn_mfma_f32_16x16x32_bf16(af[i], bfr[j], acc[i][j], 0, 0, 0);
        __syncthreads();
        buf ^= 1;
    }
    const int lg = lane >> 4;
#pragma unroll
    for (int j = 0; j < 4; ++j) {
        int col = col0 + wn * 64 + j * 16 + lr;
        float bias = bskip[col] + bmix[col];
#pragma unroll
        for (int i = 0; i < 4; ++i) {
            int rbase = row0 + wm * 64 + i * 16 + lg * 4;
#pragma unroll
            for (int r = 0; r < 4; ++r)
                out[(size_t)(rbase + r) * DOUT + col] = acc[i][j][r] + bias;
        }
    }
}

extern "C" void kernel_launch(void* const* d_in, const int* in_sizes, int n_in,
                              void* d_out, int out_size, void* d_ws, size_t ws_size,
                              hipStream_t stream) {
    const float* x        = (const float*)d_in[0];
    const float* state_re = (const float*)d_in[1];
    const float* state_im = (const float*)d_in[2];
    const int*   start    = (const int*)d_in[3];
    const float* W_pre    = (const float*)d_in[5];
    const float* b_pre    = (const float*)d_in[6];
    const float* W_skip   = (const float*)d_in[7];
    const float* b_skip   = (const float*)d_in[8];
    const float* W_mix    = (const float*)d_in[9];
    const float* b_mix    = (const float*)d_in[10];
    const float* a_dec    = (const float*)d_in[11];
    const float* b_freq   = (const float*)d_in[12];

    uint8_t* ws = (uint8_t*)d_ws;
    bf16*  A         = (bf16*)(ws);                 // 8192*3072*2 = 50331648
    bf16*  Bc        = (bf16*)(ws + 50331648);      // 1024*3072*2 = 6291456
    bf16*  Wp        = (bf16*)(ws + 56623104);      // 64*1024*2   = 131072
    float* pre_raw   = (float*)(ws + 56754176);     // 8192*64*4   = 2097152
    float2* local_end= (float2*)(ws + 58851328);    // 128*1024*8  = 1048576
    float2* carry_in = (float2*)(ws + 59899904);    // 1048576
    int*   reset_any = (int*)(ws + 60948480);       // 512

    cvt_cast<<<dim3((8192 * 1024 / 4 + 255) / 256), 256, 0, stream>>>(x, A, 8192, 1024, KTOT, 0);
    cvt_cast<<<dim3((1024 * 1024 / 4 + 255) / 256), 256, 0, stream>>>(W_skip, Bc, 1024, 1024, KTOT, 0);
    cvt_cast<<<dim3((1024 * 2048 / 4 + 255) / 256), 256, 0, stream>>>(W_mix, Bc, 1024, 2048, KTOT, 1024);
    cvt_cast<<<dim3((64 * 1024 / 4 + 255) / 256), 256, 0, stream>>>(W_pre, Wp, 64, 1024, 1024, 0);

    gemm_pre<<<dim3(64), 256, 0, stream>>>(A, Wp, b_pre, pre_raw);
    scan_phase1<<<dim3(NCHUNK), 256, 0, stream>>>(pre_raw, start, a_dec, b_freq, local_end, reset_any);
    int tail_n = out_size - 8192 * 1024;
    if (tail_n < 0) tail_n = 0;
    if (tail_n > 2048) tail_n = 2048;
    scan_phase2<<<dim3(1), 1024, 0, stream>>>(local_end, reset_any, state_re, state_im, a_dec, b_freq,
                                              carry_in, (float*)d_out + 8192 * 1024, tail_n);
    scan_phase3<<<dim3(NCHUNK), 256, 0, stream>>>(pre_raw, start, a_dec, b_freq, carry_in, A);
    gemm_main<<<dim3(512), 256, 0, stream>>>(A, Bc, b_skip, b_mix, (float*)d_out);
}